// Round 6
// baseline (540.995 us; speedup 1.0000x reference)
//
#include <hip/hip_runtime.h>

typedef unsigned short ushort_t;
typedef unsigned int uint_t;
typedef __bf16 bf16x8 __attribute__((ext_vector_type(8)));
typedef float float4v __attribute__((ext_vector_type(4)));
typedef uint_t uint4v __attribute__((ext_vector_type(4)));
typedef uint_t uint2v __attribute__((ext_vector_type(2)));

#define EPS 1e-6f

// Workspace layout (bytes)
#define WS_STYLE   0            // 16*512 f32 = 32 KB
#define WS_INVD    32768        // 16*512 f32 = 32 KB
#define WS_WSQ     65536        // 512*512 f32 = 1 MB
#define WS_AW      1114112      // 512*4608 bf16 = 4,718,592 B
#define WS_XP      6291456      // 16*66*66*512 bf16 = 71,368,704 B

__device__ __forceinline__ ushort_t f2bf(float v) {
    union { float f; uint_t u; } c; c.f = v;
    uint_t u = c.u;
    u += 0x7fffu + ((u >> 16) & 1u);   // round-to-nearest-even
    return (ushort_t)(u >> 16);
}

__device__ __forceinline__ void gload_lds16(const void* g, void* l) {
    __builtin_amdgcn_global_load_lds(
        (const __attribute__((address_space(1))) uint_t*)g,
        (__attribute__((address_space(3))) uint_t*)l, 16, 0, 0);
}

// ---------------- L1 (fused): style GEMV + weight cast/permute ----------------
__global__ void prep_fused1(const float* __restrict__ w, const float* __restrict__ lw,
                            const float* __restrict__ lb, const float* __restrict__ cw,
                            float* __restrict__ style, ushort_t* __restrict__ Aw,
                            float* __restrict__ wsq) {
    int blk = blockIdx.x;
    if (blk < 2048) {
        int gw = blk * 4 + (threadIdx.x >> 6);   // 0..8191
        int lane = threadIdx.x & 63;
        int b = gw >> 9, o = gw & 511;
        float s = 0.f;
#pragma unroll
        for (int j = 0; j < 8; ++j) {
            int d = j * 64 + lane;
            s += w[b * 512 + d] * lw[o * 512 + d];
        }
#pragma unroll
        for (int off = 32; off; off >>= 1) s += __shfl_down(s, off);
        if (lane == 0) style[gw] = s + lb[o];
    } else {
        int id = (blk - 2048) * 256 + threadIdx.x;   // o*512 + i
        int o = id >> 9, i = id & 511;
        const float* p = cw + (size_t)id * 9;
        size_t base = (size_t)o * 4608 + (size_t)(i >> 6) * 576 + (i & 63);
        float s = 0.f;
#pragma unroll
        for (int t = 0; t < 9; ++t) {
            float v = p[t];
            s += v * v;
            Aw[base + t * 64] = f2bf(v);
        }
        wsq[id] = s;
    }
}

// ---------------- L2 (fused): inv_denom + border zero + modulate/transpose ----------------
__global__ void prep_fused2(const float* __restrict__ wsq, const float* __restrict__ style,
                            float* __restrict__ invd, const float* __restrict__ x,
                            ushort_t* __restrict__ Xp) {
    __shared__ ushort_t tile[64][66];   // modulate branch only
    int blk = blockIdx.x;
    if (blk < 2048) {
        // invd[b][o] = rsqrt(sum_i wsq[o][i]*style[b][i]^2 + eps)
        int gw = blk * 4 + (threadIdx.x >> 6);
        int lane = threadIdx.x & 63;
        int b = gw >> 9, o = gw & 511;
        float s = 0.f;
#pragma unroll
        for (int j = 0; j < 8; ++j) {
            int d = j * 64 + lane;
            float st = style[b * 512 + d];
            s += wsq[o * 512 + d] * st * st;
        }
#pragma unroll
        for (int off = 32; off; off >>= 1) s += __shfl_down(s, off);
        if (lane == 0) invd[gw] = rsqrtf(s + EPS);
    } else if (blk < 3088) {
        // zero the 1-px padding border of Xp (NHWC, 66x66); 4 border-pixels/block
        int j = (blk - 2048) * 4 + (threadIdx.x >> 6);   // 0..4159
        int lane = threadIdx.x & 63;
        int b = j / 260, bp = j - b * 260;
        int py, px;
        if (bp < 66)       { py = 0;        px = bp; }
        else if (bp < 132) { py = 65;       px = bp - 66; }
        else if (bp < 196) { py = bp - 131; px = 0; }
        else               { py = bp - 195; px = 65; }
        size_t pix = ((size_t)b * 66 + py) * 66 + px;
        ((uint4v*)(Xp + pix * 512))[lane] = (uint4v){0, 0, 0, 0};
    } else {
        // Xp[b][y+1][x+1][i] = bf16(x[b][i][y][x] * style[b][i])  (NHWC interior)
        int mb = blk - 3088;          // 0..8191
        int y = mb & 63;
        int chunk = mb >> 6;          // 0..127
        int i0 = (chunk & 7) * 64;
        int b = chunk >> 3;
        int tid = threadIdx.x;
        int ch = tid >> 2;            // 0..63 channel within tile
        int xq = tid & 3;             // x-quarter slot
        float s = style[b * 512 + i0 + ch];
        const float* xrow = x + (((size_t)b * 512 + i0 + ch) * 64 + y) * 64;
#pragma unroll
        for (int pass = 0; pass < 4; ++pass) {
            int x0 = pass * 16 + xq * 4;
            float4v v = *(const float4v*)(xrow + x0);
            ushort_t u[4];
#pragma unroll
            for (int j = 0; j < 4; ++j) u[j] = f2bf(v[j] * s);
            *(uint2v*)(&tile[ch][x0]) = *(const uint2v*)u;
        }
        __syncthreads();
        size_t rowbase = ((size_t)b * 66 + (y + 1)) * 66 + 1;
#pragma unroll
        for (int pass = 0; pass < 2; ++pass) {
            int idx = pass * 256 + tid;
            int xx = idx >> 3;        // 0..63
            int ch8 = idx & 7;        // 8-channel chunk
            ushort_t v[8];
#pragma unroll
            for (int j = 0; j < 8; ++j) v[j] = tile[ch8 * 8 + j][xx];
            *(uint4v*)(Xp + (rowbase + xx) * 512 + i0 + ch8 * 8) = *(uint4v*)v;
        }
    }
}

// ---------------- Main implicit-GEMM conv: per batch M=512, N=4096, K=4608 ----------------
// 256x128 tile, BK=32, 256 threads (4 waves, 2M x 2N), per-wave 128x64 output.
// LDS 48 KB/block -> TWO blocks per CU: two desynced blocks cover each other's
// barrier/waitcnt drains (r3/r4 showed intra-block scheduling can't: ~4500
// cyc/K-tile serial floor with one 128KB block/CU).
// r5 bugfixes: (1) bga0 had the padded +1 offsets baked in TWICE (boff's dh,dw in
// 0..2 already encode the -1..+1 tap range relative to the UNSHIFTED base) ->
// every tap read pixel (+1,+1), absmax 7.8. Base is now unshifted, as in r2-r4.
// (2) 64-B LDS rows have a 2-row bank period; slot = quad ^ (row&3) left lanes
// {0,4,8,12} on the same banks (4-way conflict). New involution f(row) =
// (row ^ (row>>2)) & 3 spreads them; 16-lane group -> 8 positions x 2 = free.
// Same involution applied on store (source-granule pre-swizzle, s-independent)
// and read sides.
// Per K-tile: stage(kt+1) -> freed buffer; counted vmcnt(6); barrier; 12x
// ds_read_b128; 32 MFMA (setprio); barrier. K order: kt = iblk*18 + t*2 + h
// (64-ch block outer, tap inner, 32-ch half) -- L2-resident B reuse. XCD remap:
// one batch concurrent per XCD.
__global__ __launch_bounds__(256, 2) void conv_gemm(const ushort_t* __restrict__ Aw,
                                                    const ushort_t* __restrict__ Xp,
                                                    const float* __restrict__ invd,
                                                    float* __restrict__ out) {
    __shared__ ushort_t As[2][8192];    // [parity][256 rows x 32 k], 16 KB each
    __shared__ ushort_t Bs[2][4096];    // [parity][128 rows x 32 k], 8 KB each

    const int tid  = threadIdx.x;
    const int lane = tid & 63;
    const int wv   = tid >> 6;      // 0..3
    const int wm   = wv >> 1;       // 0..1  (M half)
    const int wn   = wv & 1;        // 0..1  (N half)
    const int l15  = lane & 15;
    const int quad = lane >> 4;

    // XCD-aware bijective remap: 1024 blocks = 8 XCD x 128; concurrent 64 blocks
    // per XCD (2/CU x 32 CU) = one batch (2 o-tiles x 32 p-tiles); 2 batches/XCD.
    const int bid = blockIdx.x;
    const int xcd = bid & 7;
    const int ci  = bid >> 3;           // 0..127
    const int b   = xcd * 2 + (ci >> 6);
    const int ot  = (ci >> 5) & 1;
    const int pt  = ci & 31;            // p-tile 0..31 (128 px each)
    const int o0  = ot * 256;
    const int p0  = pt * 128;

    // staging: granule q = s*256 + tid; row = s*64 + (tid>>2), stored slot = tid&3,
    // source chunk = slot ^ f(row), f(row) = (row ^ (row>>2)) & 3.
    // row&3 = tr4&3 and (row>>2)&3 = (tr4>>2)&3 (s*64 contributes 0 mod 4 to both)
    // -> source offset is s-independent.
    const int tr4 = tid >> 2;                            // 0..63
    const int gsw = (((tid & 3) ^ ((tr4 ^ (tr4 >> 2)) & 3)) << 4);
    const char* aga0 = (const char*)Aw + (size_t)(o0 + tr4) * 9216 + gsw;
    const char* bga0 = (const char*)Xp + ((size_t)(b * 66 + pt * 2) * 66 + tr4) * 1024 + gsw;
    const int lds_wv = wv * 1024;                        // wave-uniform byte base per stage chunk

    // read-side frag addresses: row r = base16 + l15 (base16 % 16 == 0), so
    // f(r) = (l15 ^ (l15>>2)) & 3, uniform across mi/ni.
    const int sw    = ((quad ^ ((l15 ^ (l15 >> 2)) & 3)) << 4);
    const int aoffs = (wm * 128 + l15) * 64;             // + mi*1024
    const int boffs = (wn * 64 + l15) * 64;              // + ni*1024

    float4v acc[8][4] = {};

    auto stage = [&](int kt2) {
        const int parity = kt2 & 1;
        const int iblk = (kt2 * 3641) >> 16;             // floor(kt2/18), kt2 < 144
        const int rem  = kt2 - iblk * 18;
        const int t    = rem >> 1;                       // tap 0..8
        const int h    = rem & 1;                        // 32-ch half of the 64-ch block
        const int dh   = (t * 11) >> 5;                  // t/3
        const int dw   = t - dh * 3;
        const long aoff = (long)kt2 * 64;                // A contiguous in this k order
        const long boff = (long)(dh * 66 + dw) * 1024 + iblk * 128 + h * 64;
        char* la = (char*)&As[parity][0] + lds_wv;
        char* lb = (char*)&Bs[parity][0] + lds_wv;
#pragma unroll
        for (int s = 0; s < 4; ++s)
            gload_lds16(aga0 + (size_t)s * 589824 + aoff, la + s * 4096);
#pragma unroll
        for (int s = 0; s < 2; ++s)
            gload_lds16(bga0 + (size_t)s * 67584 + boff, lb + s * 4096);
    };

    stage(0);

#pragma unroll 1
    for (int kt = 0; kt < 144; ++kt) {
        if (kt < 143) {
            stage(kt + 1);                               // into freed buffer (end-barrier of kt-1)
            asm volatile("s_waitcnt vmcnt(6)" ::: "memory");   // stage(kt) landed; kt+1 in flight
        } else {
            asm volatile("s_waitcnt vmcnt(0)" ::: "memory");
        }
        __builtin_amdgcn_s_barrier();                    // block-wide: tile kt certified

        const char* ab = (const char*)&As[kt & 1][0];
        const char* bb = (const char*)&Bs[kt & 1][0];
        bf16x8 av[8], bv[4];
#pragma unroll
        for (int mi = 0; mi < 8; ++mi)
            av[mi] = *(const bf16x8*)(ab + aoffs + mi * 1024 + sw);
#pragma unroll
        for (int ni = 0; ni < 4; ++ni)
            bv[ni] = *(const bf16x8*)(bb + boffs + ni * 1024 + sw);

        __builtin_amdgcn_s_setprio(1);
#pragma unroll
        for (int mi = 0; mi < 8; ++mi)
#pragma unroll
            for (int ni = 0; ni < 4; ++ni)
                acc[mi][ni] = __builtin_amdgcn_mfma_f32_16x16x32_bf16(av[mi], bv[ni], acc[mi][ni], 0, 0, 0);
        __builtin_amdgcn_s_setprio(0);

        __builtin_amdgcn_s_barrier();                    // all reads of buf[kt&1] done -> free
    }

    // epilogue: out[b][o][p] = acc * inv_denom[b][o]
    const float* invb = invd + b * 512 + o0 + wm * 128;
    float* outb = out + ((size_t)b * 512 + o0 + wm * 128) * 4096 + p0 + wn * 64;
#pragma unroll
    for (int mi = 0; mi < 8; ++mi) {
#pragma unroll
        for (int r = 0; r < 4; ++r) {
            int m = mi * 16 + quad * 4 + r;
            float d = invb[m];
#pragma unroll
            for (int ni = 0; ni < 4; ++ni) {
                int n = ni * 16 + l15;
                outb[(size_t)m * 4096 + n] = acc[mi][ni][r] * d;
            }
        }
    }
}

extern "C" void kernel_launch(void* const* d_in, const int* in_sizes, int n_in,
                              void* d_out, int out_size, void* d_ws, size_t ws_size,
                              hipStream_t stream) {
    const float* x  = (const float*)d_in[0];   // (16,512,64,64)
    const float* w  = (const float*)d_in[1];   // (16,512)
    const float* cw = (const float*)d_in[2];   // (512,512,3,3)
    const float* lw = (const float*)d_in[3];   // (512,512)
    const float* lb = (const float*)d_in[4];   // (512,)
    float* out = (float*)d_out;

    char* ws = (char*)d_ws;
    float*    style = (float*)(ws + WS_STYLE);
    float*    invd  = (float*)(ws + WS_INVD);
    float*    wsq   = (float*)(ws + WS_WSQ);
    ushort_t* Aw    = (ushort_t*)(ws + WS_AW);
    ushort_t* Xp    = (ushort_t*)(ws + WS_XP);

    prep_fused1<<<3072, 256, 0, stream>>>(w, lw, lb, cw, style, Aw, wsq);
    prep_fused2<<<11280, 256, 0, stream>>>(wsq, style, invd, x, Xp);
    conv_gemm<<<1024, 256, 0, stream>>>(Aw, Xp, invd, out);
}

// Round 7
// 537.925 us; speedup vs baseline: 1.0057x; 1.0057x over previous
//
#include <hip/hip_runtime.h>

typedef unsigned short ushort_t;
typedef unsigned int uint_t;
typedef __bf16 bf16x8 __attribute__((ext_vector_type(8)));
typedef float float4v __attribute__((ext_vector_type(4)));
typedef uint_t uint4v __attribute__((ext_vector_type(4)));
typedef uint_t uint2v __attribute__((ext_vector_type(2)));

#define EPS 1e-6f

// Workspace layout (bytes)
#define WS_STYLE   0            // 16*512 f32 = 32 KB
#define WS_INVD    32768        // 16*512 f32 = 32 KB
#define WS_WSQ     65536        // 512*512 f32 = 1 MB
#define WS_AW      1114112      // 512*4608 bf16 = 4,718,592 B
#define WS_XP      6291456      // 16*66*66*512 bf16 = 71,368,704 B

__device__ __forceinline__ ushort_t f2bf(float v) {
    union { float f; uint_t u; } c; c.f = v;
    uint_t u = c.u;
    u += 0x7fffu + ((u >> 16) & 1u);   // round-to-nearest-even
    return (ushort_t)(u >> 16);
}

__device__ __forceinline__ void gload_lds16(const void* g, void* l) {
    __builtin_amdgcn_global_load_lds(
        (const __attribute__((address_space(1))) uint_t*)g,
        (__attribute__((address_space(3))) uint_t*)l, 16, 0, 0);
}

// ---------------- L1 (fused): style GEMV + weight cast/permute ----------------
__global__ void prep_fused1(const float* __restrict__ w, const float* __restrict__ lw,
                            const float* __restrict__ lb, const float* __restrict__ cw,
                            float* __restrict__ style, ushort_t* __restrict__ Aw,
                            float* __restrict__ wsq) {
    int blk = blockIdx.x;
    if (blk < 2048) {
        int gw = blk * 4 + (threadIdx.x >> 6);   // 0..8191
        int lane = threadIdx.x & 63;
        int b = gw >> 9, o = gw & 511;
        float s = 0.f;
#pragma unroll
        for (int j = 0; j < 8; ++j) {
            int d = j * 64 + lane;
            s += w[b * 512 + d] * lw[o * 512 + d];
        }
#pragma unroll
        for (int off = 32; off; off >>= 1) s += __shfl_down(s, off);
        if (lane == 0) style[gw] = s + lb[o];
    } else {
        int id = (blk - 2048) * 256 + threadIdx.x;   // o*512 + i
        int o = id >> 9, i = id & 511;
        const float* p = cw + (size_t)id * 9;
        size_t base = (size_t)o * 4608 + (size_t)(i >> 6) * 576 + (i & 63);
        float s = 0.f;
#pragma unroll
        for (int t = 0; t < 9; ++t) {
            float v = p[t];
            s += v * v;
            Aw[base + t * 64] = f2bf(v);
        }
        wsq[id] = s;
    }
}

// ---------------- L2 (fused): inv_denom + border zero + modulate/transpose ----------------
__global__ void prep_fused2(const float* __restrict__ wsq, const float* __restrict__ style,
                            float* __restrict__ invd, const float* __restrict__ x,
                            ushort_t* __restrict__ Xp) {
    __shared__ ushort_t tile[64][66];   // modulate branch only
    int blk = blockIdx.x;
    if (blk < 2048) {
        // invd[b][o] = rsqrt(sum_i wsq[o][i]*style[b][i]^2 + eps)
        int gw = blk * 4 + (threadIdx.x >> 6);
        int lane = threadIdx.x & 63;
        int b = gw >> 9, o = gw & 511;
        float s = 0.f;
#pragma unroll
        for (int j = 0; j < 8; ++j) {
            int d = j * 64 + lane;
            float st = style[b * 512 + d];
            s += wsq[o * 512 + d] * st * st;
        }
#pragma unroll
        for (int off = 32; off; off >>= 1) s += __shfl_down(s, off);
        if (lane == 0) invd[gw] = rsqrtf(s + EPS);
    } else if (blk < 3088) {
        // zero the 1-px padding border of Xp (NHWC, 66x66); 4 border-pixels/block
        int j = (blk - 2048) * 4 + (threadIdx.x >> 6);   // 0..4159
        int lane = threadIdx.x & 63;
        int b = j / 260, bp = j - b * 260;
        int py, px;
        if (bp < 66)       { py = 0;        px = bp; }
        else if (bp < 132) { py = 65;       px = bp - 66; }
        else if (bp < 196) { py = bp - 131; px = 0; }
        else               { py = bp - 195; px = 65; }
        size_t pix = ((size_t)b * 66 + py) * 66 + px;
        ((uint4v*)(Xp + pix * 512))[lane] = (uint4v){0, 0, 0, 0};
    } else {
        // Xp[b][y+1][x+1][i] = bf16(x[b][i][y][x] * style[b][i])  (NHWC interior)
        int mb = blk - 3088;          // 0..8191
        int y = mb & 63;
        int chunk = mb >> 6;          // 0..127
        int i0 = (chunk & 7) * 64;
        int b = chunk >> 3;
        int tid = threadIdx.x;
        int ch = tid >> 2;            // 0..63 channel within tile
        int xq = tid & 3;             // x-quarter slot
        float s = style[b * 512 + i0 + ch];
        const float* xrow = x + (((size_t)b * 512 + i0 + ch) * 64 + y) * 64;
#pragma unroll
        for (int pass = 0; pass < 4; ++pass) {
            int x0 = pass * 16 + xq * 4;
            float4v v = *(const float4v*)(xrow + x0);
            ushort_t u[4];
#pragma unroll
            for (int j = 0; j < 4; ++j) u[j] = f2bf(v[j] * s);
            *(uint2v*)(&tile[ch][x0]) = *(const uint2v*)u;
        }
        __syncthreads();
        size_t rowbase = ((size_t)b * 66 + (y + 1)) * 66 + 1;
#pragma unroll
        for (int pass = 0; pass < 2; ++pass) {
            int idx = pass * 256 + tid;
            int xx = idx >> 3;        // 0..63
            int ch8 = idx & 7;        // 8-channel chunk
            ushort_t v[8];
#pragma unroll
            for (int j = 0; j < 8; ++j) v[j] = tile[ch8 * 8 + j][xx];
            *(uint4v*)(Xp + (rowbase + xx) * 512 + i0 + ch8 * 8) = *(uint4v*)v;
        }
    }
}

// ---------------- Main implicit-GEMM conv: per batch M=512, N=4096, K=4608 ----------------
// 256x128 tile, BK=32, 256 threads (4 waves, 2M x 2N), per-wave 128x64 output.
// LDS 48 KB/block -> TWO blocks per CU (cross-block TLP covers barrier drains).
// r6's 64-B-row swizzle was 4-way bank-conflicted (2.8e7/dispatch, odd rows shift
// the bank window by 16). Fix: 128-B LDS rows via M-ROW-PAIR PACKING -- LDS row r
// holds M-rows {2r, 2r+1} (64 B each, 8 granules of 16 B); granule slot =
// (m&1)*4 + (c ^ (r&3)), c = k-chunk 0..3. Every row is bank-aligned at 0 (128 B)
// and each 8-lane read group hits slots {0,4,1,5,2,6,3,7}-class (all distinct,
// enumerated for all quads) -- the r1-r4 PROVEN zero-conflict class.
// Store side: linear global_load_lds dest; same involution pre-applied to the
// per-lane global source (s-independent; rule 21 both-sides-or-neither).
// Per K-tile: stage(kt+1) -> freed buffer; counted vmcnt(6); barrier; 12x
// ds_read_b128; 32 MFMA (setprio); barrier. K order: kt = iblk*18 + t*2 + h --
// L2-resident B reuse. XCD remap: one batch concurrent per XCD.
__global__ __launch_bounds__(256, 2) void conv_gemm(const ushort_t* __restrict__ Aw,
                                                    const ushort_t* __restrict__ Xp,
                                                    const float* __restrict__ invd,
                                                    float* __restrict__ out) {
    __shared__ ushort_t As[2][8192];    // [parity][128 lds-rows x 128 B] = 16 KB each
    __shared__ ushort_t Bs[2][4096];    // [parity][ 64 lds-rows x 128 B] =  8 KB each

    const int tid  = threadIdx.x;
    const int lane = tid & 63;
    const int wv   = tid >> 6;      // 0..3
    const int wm   = wv >> 1;       // 0..1  (M half)
    const int wn   = wv & 1;        // 0..1  (N half)
    const int l15  = lane & 15;
    const int quad = lane >> 4;

    // XCD-aware bijective remap: 1024 blocks = 8 XCD x 128; concurrent 64 blocks
    // per XCD (2/CU x 32 CU) = one batch (2 o-tiles x 32 p-tiles); 2 batches/XCD.
    const int bid = blockIdx.x;
    const int xcd = bid & 7;
    const int ci  = bid >> 3;           // 0..127
    const int b   = xcd * 2 + (ci >> 6);
    const int ot  = (ci >> 5) & 1;
    const int pt  = ci & 31;            // p-tile 0..31 (128 px each)
    const int o0  = ot * 256;
    const int p0  = pt * 128;

    // staging: pass s covers granules q = s*256 + tid; lds-row r = q>>3,
    // slot = tid&7. Granule (r,slot) holds m = 2r + (slot>>2), chunk
    // c = (slot&3) ^ (r&3). Per-thread (s-independent):
    //   m_loc = 2*(tid>>3) + ((tid>>2)&1)   (row within 64-row pass)
    //   c     = (tid&3) ^ ((tid>>3)&3)
    const int m_loc = 2 * (tid >> 3) + ((tid >> 2) & 1);
    const int csw   = (((tid & 3) ^ ((tid >> 3) & 3)) << 4);
    const char* aga0 = (const char*)Aw + (size_t)(o0 + m_loc) * 9216 + csw;
    const char* bga0 = (const char*)Xp + ((size_t)(b * 66 + pt * 2) * 66 + m_loc) * 1024 + csw;
    const int lds_wv = wv * 1024;       // wave-uniform byte base per stage pass

    // read-side frag addresses: M-row m = base16 + l15 -> lds-row r = base/2 +
    // (l15>>1), r&3 = (l15>>1)&3 (uniform across mi/ni since base16 % 16 == 0);
    // slot = (l15&1)*4 + (quad ^ (r&3)); byte = r*128 + slot*16.
    const int fsw   = (((l15 & 1) * 4 + (quad ^ ((l15 >> 1) & 3))) << 4);
    const int aoffs = (wm * 64 + (l15 >> 1)) * 128 + fsw;   // + mi*1024
    const int boffs = (wn * 32 + (l15 >> 1)) * 128 + fsw;   // + ni*1024

    float4v acc[8][4] = {};

    auto stage = [&](int kt2) {
        const int parity = kt2 & 1;
        const int iblk = (kt2 * 3641) >> 16;             // floor(kt2/18), kt2 < 144
        const int rem  = kt2 - iblk * 18;
        const int t    = rem >> 1;                       // tap 0..8
        const int h    = rem & 1;                        // 32-ch half of the 64-ch block
        const int dh   = (t * 11) >> 5;                  // t/3
        const int dw   = t - dh * 3;
        const long aoff = (long)kt2 * 64;                // A contiguous in this k order
        const long boff = (long)(dh * 66 + dw) * 1024 + iblk * 128 + h * 64;
        char* la = (char*)&As[parity][0] + lds_wv;
        char* lb = (char*)&Bs[parity][0] + lds_wv;
#pragma unroll
        for (int s = 0; s < 4; ++s)
            gload_lds16(aga0 + (size_t)s * 589824 + aoff, la + s * 4096);
#pragma unroll
        for (int s = 0; s < 2; ++s)
            gload_lds16(bga0 + (size_t)s * 67584 + boff, lb + s * 4096);
    };

    stage(0);

#pragma unroll 1
    for (int kt = 0; kt < 144; ++kt) {
        if (kt < 143) {
            stage(kt + 1);                               // into freed buffer (end-barrier of kt-1)
            asm volatile("s_waitcnt vmcnt(6)" ::: "memory");   // stage(kt) landed; kt+1 in flight
        } else {
            asm volatile("s_waitcnt vmcnt(0)" ::: "memory");
        }
        __builtin_amdgcn_s_barrier();                    // block-wide: tile kt certified

        const char* ab = (const char*)&As[kt & 1][0];
        const char* bb = (const char*)&Bs[kt & 1][0];
        bf16x8 av[8], bv[4];
#pragma unroll
        for (int mi = 0; mi < 8; ++mi)
            av[mi] = *(const bf16x8*)(ab + aoffs + mi * 1024);
#pragma unroll
        for (int ni = 0; ni < 4; ++ni)
            bv[ni] = *(const bf16x8*)(bb + boffs + ni * 1024);

        __builtin_amdgcn_s_setprio(1);
#pragma unroll
        for (int mi = 0; mi < 8; ++mi)
#pragma unroll
            for (int ni = 0; ni < 4; ++ni)
                acc[mi][ni] = __builtin_amdgcn_mfma_f32_16x16x32_bf16(av[mi], bv[ni], acc[mi][ni], 0, 0, 0);
        __builtin_amdgcn_s_setprio(0);

        __builtin_amdgcn_s_barrier();                    // all reads of buf[kt&1] done -> free
    }

    // epilogue: out[b][o][p] = acc * inv_denom[b][o]
    const float* invb = invd + b * 512 + o0 + wm * 128;
    float* outb = out + ((size_t)b * 512 + o0 + wm * 128) * 4096 + p0 + wn * 64;
#pragma unroll
    for (int mi = 0; mi < 8; ++mi) {
#pragma unroll
        for (int r = 0; r < 4; ++r) {
            int m = mi * 16 + quad * 4 + r;
            float d = invb[m];
#pragma unroll
            for (int ni = 0; ni < 4; ++ni) {
                int n = ni * 16 + l15;
                outb[(size_t)m * 4096 + n] = acc[mi][ni][r] * d;
            }
        }
    }
}

extern "C" void kernel_launch(void* const* d_in, const int* in_sizes, int n_in,
                              void* d_out, int out_size, void* d_ws, size_t ws_size,
                              hipStream_t stream) {
    const float* x  = (const float*)d_in[0];   // (16,512,64,64)
    const float* w  = (const float*)d_in[1];   // (16,512)
    const float* cw = (const float*)d_in[2];   // (512,512,3,3)
    const float* lw = (const float*)d_in[3];   // (512,512)
    const float* lb = (const float*)d_in[4];   // (512,)
    float* out = (float*)d_out;

    char* ws = (char*)d_ws;
    float*    style = (float*)(ws + WS_STYLE);
    float*    invd  = (float*)(ws + WS_INVD);
    float*    wsq   = (float*)(ws + WS_WSQ);
    ushort_t* Aw    = (ushort_t*)(ws + WS_AW);
    ushort_t* Xp    = (ushort_t*)(ws + WS_XP);

    prep_fused1<<<3072, 256, 0, stream>>>(w, lw, lb, cw, style, Aw, wsq);
    prep_fused2<<<11280, 256, 0, stream>>>(wsq, style, invd, x, Xp);
    conv_gemm<<<1024, 256, 0, stream>>>(Aw, Xp, invd, out);
}

// Round 11
// 482.138 us; speedup vs baseline: 1.1221x; 1.1157x over previous
//
#include <hip/hip_runtime.h>

typedef unsigned short ushort_t;
typedef unsigned int uint_t;
typedef __bf16 bf16x8 __attribute__((ext_vector_type(8)));
typedef float float4v __attribute__((ext_vector_type(4)));
typedef uint_t uint4v __attribute__((ext_vector_type(4)));
typedef uint_t uint2v __attribute__((ext_vector_type(2)));

#define EPS 1e-6f

// Workspace layout (bytes)
#define WS_STYLE   0            // 16*512 f32 = 32 KB
#define WS_INVD    32768        // 16*512 f32 = 32 KB
#define WS_WSQ     65536        // 512*512 f32 = 1 MB
#define WS_AW      1114112      // 512*4608 bf16 = 4,718,592 B
#define WS_XP      6291456      // 16*8*66*66*64 bf16 = 71,368,704 B
// Xp layout (r10 relayout): [b][iblk][py][px][64ch] -- slab = b*8+iblk, byte =
// (slab*4356 + py*66 + px)*128 + ch_in_block*2. Same total bytes as old NHWC-512;
// modulate writes and conv B-stages become contiguous at >=128B granularity.

__device__ __forceinline__ ushort_t f2bf(float v) {
    union { float f; uint_t u; } c; c.f = v;
    uint_t u = c.u;
    u += 0x7fffu + ((u >> 16) & 1u);   // round-to-nearest-even
    return (ushort_t)(u >> 16);
}

__device__ __forceinline__ void gload_lds16(const void* g, void* l) {
    __builtin_amdgcn_global_load_lds(
        (const __attribute__((address_space(1))) uint_t*)g,
        (__attribute__((address_space(3))) uint_t*)l, 16, 0, 0);
}

// ---------------- L1 (fused): style GEMV + weight cast/permute ----------------
__global__ void prep_fused1(const float* __restrict__ w, const float* __restrict__ lw,
                            const float* __restrict__ lb, const float* __restrict__ cw,
                            float* __restrict__ style, ushort_t* __restrict__ Aw,
                            float* __restrict__ wsq) {
    int blk = blockIdx.x;
    if (blk < 2048) {
        int gw = blk * 4 + (threadIdx.x >> 6);   // 0..8191
        int lane = threadIdx.x & 63;
        int b = gw >> 9, o = gw & 511;
        float s = 0.f;
#pragma unroll
        for (int j = 0; j < 8; ++j) {
            int d = j * 64 + lane;
            s += w[b * 512 + d] * lw[o * 512 + d];
        }
#pragma unroll
        for (int off = 32; off; off >>= 1) s += __shfl_down(s, off);
        if (lane == 0) style[gw] = s + lb[o];
    } else {
        int id = (blk - 2048) * 256 + threadIdx.x;   // o*512 + i
        int o = id >> 9, i = id & 511;
        const float* p = cw + (size_t)id * 9;
        size_t base = (size_t)o * 4608 + (size_t)(i >> 6) * 576 + (i & 63);
        float s = 0.f;
#pragma unroll
        for (int t = 0; t < 9; ++t) {
            float v = p[t];
            s += v * v;
            Aw[base + t * 64] = f2bf(v);
        }
        wsq[id] = s;
    }
}

// ---------------- L2 (fused): inv_denom + border zero + modulate/transpose ----------------
__global__ void prep_fused2(const float* __restrict__ wsq, const float* __restrict__ style,
                            float* __restrict__ invd, const float* __restrict__ x,
                            ushort_t* __restrict__ Xp) {
    __shared__ ushort_t tile[64][66];   // modulate branch only
    int blk = blockIdx.x;
    if (blk < 2048) {
        // invd[b][o] = rsqrt(sum_i wsq[o][i]*style[b][i]^2 + eps)
        int gw = blk * 4 + (threadIdx.x >> 6);
        int lane = threadIdx.x & 63;
        int b = gw >> 9, o = gw & 511;
        float s = 0.f;
#pragma unroll
        for (int j = 0; j < 8; ++j) {
            int d = j * 64 + lane;
            float st = style[b * 512 + d];
            s += wsq[o * 512 + d] * st * st;
        }
#pragma unroll
        for (int off = 32; off; off >>= 1) s += __shfl_down(s, off);
        if (lane == 0) invd[gw] = rsqrtf(s + EPS);
    } else if (blk < 3088) {
        // zero the 1-px padding border: 128 slabs x 260 border px x 128 B.
        // 1040 blocks x 256 threads x 16 B = exactly 128*260*128 B.
        int j = blk - 2048;                      // 0..1039
        int E = j * 32 + (threadIdx.x >> 3);     // border-pixel entry 0..33279
        int g = threadIdx.x & 7;                 // 16-B granule within 128-B pixel
        int slab = E / 260;                      // 0..127 (b*8 + iblk)
        int bp = E - slab * 260;
        int py, px;
        if (bp < 66)       { py = 0;        px = bp; }
        else if (bp < 132) { py = 65;       px = bp - 66; }
        else if (bp < 196) { py = bp - 131; px = 0; }
        else               { py = bp - 195; px = 65; }
        size_t byte = ((size_t)slab * 4356 + py * 66 + px) * 128 + g * 16;
        *(uint4v*)((char*)Xp + byte) = (uint4v){0, 0, 0, 0};
    } else {
        // Xp[slab(b,iblk)][y+1][x+1][ch] = bf16(x[b][iblk*64+ch][y][x]*style[...])
        // Writes are one fully-contiguous 8-KB stream per block (was 128-B
        // scatter at 1-KB stride in the old NHWC-512 layout).
        int mb = blk - 3088;          // 0..8191
        int y = mb & 63;
        int chunk = mb >> 6;          // 0..127
        int iblk = chunk & 7;
        int b = chunk >> 3;
        int i0 = iblk * 64;
        int tid = threadIdx.x;
        int ch = tid >> 2;            // 0..63 channel within block
        int xq = tid & 3;             // x-quarter slot
        float s = style[b * 512 + i0 + ch];
        const float* xrow = x + (((size_t)b * 512 + i0 + ch) * 64 + y) * 64;
#pragma unroll
        for (int pass = 0; pass < 4; ++pass) {
            int x0 = pass * 16 + xq * 4;
            float4v v = *(const float4v*)(xrow + x0);
            ushort_t u[4];
#pragma unroll
            for (int j = 0; j < 4; ++j) u[j] = f2bf(v[j] * s);
            *(uint2v*)(&tile[ch][x0]) = *(const uint2v*)u;
        }
        __syncthreads();
        size_t rowbase = ((size_t)(b * 8 + iblk) * 4356 + (y + 1) * 66 + 1) * 128;
#pragma unroll
        for (int pass = 0; pass < 2; ++pass) {
            int idx = pass * 256 + tid;
            int xx = idx >> 3;        // 0..63 pixel
            int ch8 = idx & 7;        // 8-channel chunk
            ushort_t v[8];
#pragma unroll
            for (int j = 0; j < 8; ++j) v[j] = tile[ch8 * 8 + j][xx];
            *(uint4v*)((char*)Xp + rowbase + (size_t)xx * 128 + ch8 * 16) = *(uint4v*)v;
        }
    }
}

// ---------------- Main implicit-GEMM conv: per batch M=512, N=4096, K=4608 ----------------
// VERBATIM r3 kernel (verified pass, 266.6 us) except B addressing adapted to the
// [b][iblk][py][px][64ch] Xp relayout: boff = iblk*557568 + (dh*66+dw)*128, pass
// stride s*8448. Byte = [(b*8+iblk)*4356 + (pxt*4+s+dh)*66 + (tr+dw)]*128 +
// chunk*16 -- identical tap semantics to r2-r4, identical LDS rows/swizzle/reads.
// 256x256 tile, BK=64, 512 threads (8 waves, 2M x 4N), per-wave 128x64 output.
// Cross-barrier read pipelining, ONE barrier per K-tile:
//   Region A: ds_read ks1(kt) frags (12) interleaved with 32 MFMA on preloaded ks0;
//   lgkmcnt(0) + vmcnt(0) (stage(kt+1) landed, issued a full K-tile earlier) +
//   s_barrier;
//   Region B: ds_read ks0(kt+1) from the OTHER buffer (no WAR with the stage) ||
//   issue stage(kt+2) into buf[kt&1] || 32 MFMA on ks1 (zero read-wait).
// K order channel-block-outer/tap-inner (L2-resident B reuse); XCD remap: one
// batch concurrent per XCD. LDS granule-slot XOR swizzle (0 conflicts measured).
__global__ __launch_bounds__(512, 2) void conv_gemm(const ushort_t* __restrict__ Aw,
                                                    const ushort_t* __restrict__ Xp,
                                                    const float* __restrict__ invd,
                                                    float* __restrict__ out) {
    __shared__ ushort_t lds[2][32768];   // per buf: A [0,32KB), B [32KB,64KB)

    const int tid  = threadIdx.x;
    const int lane = tid & 63;
    const int wv   = tid >> 6;      // 0..7
    const int wm   = wv >> 2;       // 0..1  (M half)
    const int wn   = wv & 3;        // 0..3  (N quarter)
    const int l15  = lane & 15;
    const int quad = lane >> 4;

    // XCD-aware bijective remap: one batch concurrent per XCD.
    const int bid = blockIdx.x;
    const int xcd = bid & 7;
    const int ci  = bid >> 3;
    const int b   = xcd * 2 + (ci >> 5);
    const int ot  = (ci >> 4) & 1;
    const int pxt = ci & 15;
    const int o0  = ot * 256;
    const int p0  = pxt * 256;

    // staging: thread tid covers granule q = s*512+tid; row = s*64+(tid>>3),
    // stored slot = tid&7, source granule = slot ^ (row&7)
    const int tr  = tid >> 3;                           // 0..63
    const int gsw = (((tid & 7) ^ (tr & 7)) << 4);
    const char* aga0 = (const char*)Aw + (size_t)(o0 + tr) * 9216 + gsw;
    const char* bga0 = (const char*)Xp
        + ((size_t)(b * 8) * 4356 + (size_t)(pxt * 4) * 66 + tr) * 128 + gsw;
    const int lds_wv = wv * 1024;

    // read-side (frag) addresses
    const int sw0 = ((quad ^ (l15 & 7)) << 4);
    const int sw1 = (((4 + quad) ^ (l15 & 7)) << 4);
    const int aoffs = (wm * 128 + l15) * 128;           // + mi*2048
    const int boffs = 32768 + (wn * 64 + l15) * 128;    // + ni*2048

    float4v acc[8][4] = {};
    bf16x8 a0[8], b0[4], a1[8], b1[4];

    auto stage = [&](int kt2) {
        const int parity = kt2 & 1;
        const long aoff = (long)kt2 * 128;
        const int iblk = (kt2 * 7282) >> 16;            // floor(kt2/9)
        const int t = kt2 - iblk * 9;
        const int dh = t / 3, dw = t - dh * 3;
        const long boff = (long)iblk * 557568 + (long)(dh * 66 + dw) * 128;
        char* la = (char*)&lds[parity][0]     + lds_wv;
        char* lb = (char*)&lds[parity][16384] + lds_wv;
#pragma unroll
        for (int s = 0; s < 4; ++s) {
            gload_lds16(aga0 + (size_t)s * 589824 + aoff, la + s * 8192);
            gload_lds16(bga0 + (size_t)s * 8448   + boff, lb + s * 8192);
        }
    };

    // prologue: prime 2 K-tiles, certify tile 0, preload ks0(0) frags
    stage(0);
    stage(1);
    asm volatile("s_waitcnt vmcnt(8)" ::: "memory");
    __builtin_amdgcn_s_barrier();
    {
        const char* base = (const char*)&lds[0][0];
#pragma unroll
        for (int ni = 0; ni < 4; ++ni) b0[ni] = *(const bf16x8*)(base + boffs + ni * 2048 + sw0);
#pragma unroll
        for (int mi = 0; mi < 8; ++mi) a0[mi] = *(const bf16x8*)(base + aoffs + mi * 2048 + sw0);
    }

#pragma unroll 1
    for (int kt = 0; kt < 72; ++kt) {
        const char* cbase = (const char*)&lds[kt & 1][0];

        // Region A: ks1 reads flow under h0 MFMAs
#pragma unroll
        for (int ni = 0; ni < 4; ++ni) b1[ni] = *(const bf16x8*)(cbase + boffs + ni * 2048 + sw1);
#pragma unroll
        for (int mi = 0; mi < 8; ++mi) a1[mi] = *(const bf16x8*)(cbase + aoffs + mi * 2048 + sw1);

        __builtin_amdgcn_s_setprio(1);
#pragma unroll
        for (int mi = 0; mi < 8; ++mi)
#pragma unroll
            for (int ni = 0; ni < 4; ++ni)
                acc[mi][ni] = __builtin_amdgcn_mfma_f32_16x16x32_bf16(a0[mi], b0[ni], acc[mi][ni], 0, 0, 0);
        __builtin_amdgcn_s_setprio(0);

        asm volatile("s_waitcnt lgkmcnt(0)" ::: "memory");   // all my buf[kt&1] reads done
        asm volatile("s_waitcnt vmcnt(0)" ::: "memory");     // stage(kt+1) landed (1-tile slack)
        __builtin_amdgcn_s_barrier();

        // Region B: next-tile ks0 reads (other buffer) || stage || h1 MFMAs
        if (kt < 71) {
            const char* nbase = (const char*)&lds[(kt + 1) & 1][0];
#pragma unroll
            for (int ni = 0; ni < 4; ++ni) b0[ni] = *(const bf16x8*)(nbase + boffs + ni * 2048 + sw0);
#pragma unroll
            for (int mi = 0; mi < 8; ++mi) a0[mi] = *(const bf16x8*)(nbase + aoffs + mi * 2048 + sw0);
        }
        if (kt < 70) stage(kt + 2);

        __builtin_amdgcn_s_setprio(1);
#pragma unroll
        for (int mi = 0; mi < 8; ++mi)
#pragma unroll
            for (int ni = 0; ni < 4; ++ni)
                acc[mi][ni] = __builtin_amdgcn_mfma_f32_16x16x32_bf16(a1[mi], b1[ni], acc[mi][ni], 0, 0, 0);
        __builtin_amdgcn_s_setprio(0);
    }

    // epilogue: out[b][o][p] = acc * inv_denom[b][o]
    const float* invb = invd + b * 512 + o0 + wm * 128;
    float* outb = out + ((size_t)b * 512 + o0 + wm * 128) * 4096 + p0 + wn * 64;
#pragma unroll
    for (int mi = 0; mi < 8; ++mi) {
#pragma unroll
        for (int r = 0; r < 4; ++r) {
            int m = mi * 16 + quad * 4 + r;
            float d = invb[m];
#pragma unroll
            for (int ni = 0; ni < 4; ++ni) {
                int n = ni * 16 + l15;
                outb[(size_t)m * 4096 + n] = acc[mi][ni][r] * d;
            }
        }
    }
}

extern "C" void kernel_launch(void* const* d_in, const int* in_sizes, int n_in,
                              void* d_out, int out_size, void* d_ws, size_t ws_size,
                              hipStream_t stream) {
    const float* x  = (const float*)d_in[0];   // (16,512,64,64)
    const float* w  = (const float*)d_in[1];   // (16,512)
    const float* cw = (const float*)d_in[2];   // (512,512,3,3)
    const float* lw = (const float*)d_in[3];   // (512,512)
    const float* lb = (const float*)d_in[4];   // (512,)
    float* out = (float*)d_out;

    char* ws = (char*)d_ws;
    float*    style = (float*)(ws + WS_STYLE);
    float*    invd  = (float*)(ws + WS_INVD);
    float*    wsq   = (float*)(ws + WS_WSQ);
    ushort_t* Aw    = (ushort_t*)(ws + WS_AW);
    ushort_t* Xp    = (ushort_t*)(ws + WS_XP);

    prep_fused1<<<3072, 256, 0, stream>>>(w, lw, lb, cw, style, Aw, wsq);
    prep_fused2<<<11280, 256, 0, stream>>>(wsq, style, invd, x, Xp);
    conv_gemm<<<512, 512, 0, stream>>>(Aw, Xp, invd, out);
}